// Round 1
// baseline (416.345 us; speedup 1.0000x reference)
//
#include <hip/hip_runtime.h>
#include <cstddef>
#include <math.h>

#define IMG_H 800
#define IMG_W 1216
#define FH 25
#define FWW 38
#define CC 2048
#define NBOX 2000
#define NKEEP 8
#define D1 100352   /* CC*49 */
#define K1 4096
#define NSLICE 16
#define DPS (D1/NSLICE)  /* 6272 */

// ---------------------------------------------------------------------------
// Kernel 1: greedy NMS (exact replica of reference loop) + ROI quantization.
// Single block; rois/scores staged in LDS (2000 boxes).
// ---------------------------------------------------------------------------
__global__ __launch_bounds__(256) void nms_sel_kernel(const float* __restrict__ rois,
                                                      const float* __restrict__ scores,
                                                      int* __restrict__ roi_out) {
    __shared__ float4 s_box[NBOX];
    __shared__ float  s_fg[NBOX];
    __shared__ float  red_v[256];
    __shared__ int    red_i[256];
    __shared__ int    s_sels[NKEEP];
    const int tid = threadIdx.x;

    for (int i = tid; i < NBOX; i += 256) {
        float x1 = rois[i*4+0], y1 = rois[i*4+1], x2 = rois[i*4+2], y2 = rois[i*4+3];
        s_box[i] = make_float4(x1, y1, x2, y2);
        bool valid = (x1 >= 0.f) && (y1 >= 0.f) && (x2 <= (float)IMG_W) && (y2 <= (float)IMG_H);
        s_fg[i] = valid ? scores[i*2+1] : -INFINITY;
    }
    __syncthreads();

    for (int it = 0; it < NKEEP; ++it) {
        // block argmax with first-index tie-break (matches jnp.argmax)
        float bv = -INFINITY; int bi = NBOX;
        for (int i = tid; i < NBOX; i += 256) {
            float v = s_fg[i];
            if (v > bv || (v == bv && i < bi)) { bv = v; bi = i; }
        }
        red_v[tid] = bv; red_i[tid] = bi;
        __syncthreads();
        for (int off = 128; off > 0; off >>= 1) {
            if (tid < off) {
                float v = red_v[tid+off]; int ii = red_i[tid+off];
                if (v > red_v[tid] || (v == red_v[tid] && ii < red_i[tid])) {
                    red_v[tid] = v; red_i[tid] = ii;
                }
            }
            __syncthreads();
        }
        int s = red_i[0];
        if (s >= NBOX) s = 0;   // all -inf -> argmax returns 0 (matches jnp)
        if (tid == 0) s_sels[it] = s;

        float4 bs = s_box[s];
        float a1 = (bs.z - bs.x) * (bs.w - bs.y);
        for (int i = tid; i < NBOX; i += 256) {
            float4 b = s_box[i];
            float ix1 = fmaxf(bs.x, b.x), iy1 = fmaxf(bs.y, b.y);
            float ix2 = fminf(bs.z, b.z), iy2 = fminf(bs.w, b.w);
            float inter = fmaxf(ix2 - ix1, 0.f) * fmaxf(iy2 - iy1, 0.f);
            float a2 = (b.z - b.x) * (b.w - b.y);
            float iou = inter / (a1 + a2 - inter);
            if (!(iou <= 0.6f)) s_fg[i] = -INFINITY;   // alive &= iou<=thresh
        }
        __syncthreads();
    }

    if (tid < NKEEP) {
        int s = s_sels[tid];
        float4 b = s_box[s];
        int x = (int)floorf(b.x / 32.0f + 0.5f);
        int y = (int)floorf(b.y / 32.0f + 0.5f);
        int w = (int)floorf(b.z / 32.0f + 1.0f);
        int h = (int)floorf(b.w / 32.0f + 1.0f);
        bool bad = (x < 0) || (x >= FWW) || (y < 0) || (y >= FH) ||
                   (w < 1) || (x + w > FWW) || (h < 1) || (y + h > FH);
        if (bad) { x = 0; y = 0; w = FWW; h = FH; }
        roi_out[tid*4+0] = x; roi_out[tid*4+1] = y;
        roi_out[tid*4+2] = w; roi_out[tid*4+3] = h;
    }
}

// ---------------------------------------------------------------------------
// Kernel 2: adaptive 7x7 max-pool. One thread per (roi, channel, cell).
// pooled flat layout: idx = r*D1 + c*49 + i*7 + j  (matches reshape(N_KEEP,-1))
// ---------------------------------------------------------------------------
__global__ __launch_bounds__(256) void roi_pool_kernel(const float* __restrict__ feat,
                                                       const int* __restrict__ roi_out,
                                                       float* __restrict__ pooled) {
    int idx = blockIdx.x * 256 + threadIdx.x;
    if (idx >= NKEEP * D1) return;
    int r    = idx / D1;
    int rem  = idx - r * D1;
    int c    = rem / 49;
    int cell = rem - c * 49;
    int i = cell / 7;
    int j = cell - i * 7;
    int x = roi_out[r*4+0], y = roi_out[r*4+1], w = roi_out[r*4+2], h = roi_out[r*4+3];
    int r0 = y + (i * h) / 7;
    int r1 = y + ((i + 1) * h + 6) / 7;
    int c0 = x + (j * w) / 7;
    int c1 = x + ((j + 1) * w + 6) / 7;
    const float* fc = feat + (size_t)c * (FH * FWW);
    float m = -INFINITY;
    for (int rr = r0; rr < r1; ++rr) {
        const float* fr = fc + rr * FWW;
        for (int cc2 = c0; cc2 < c1; ++cc2) m = fmaxf(m, fr[cc2]);
    }
    pooled[idx] = m;
}

// ---------------------------------------------------------------------------
// Kernel 3: o[n][k] = b[k]  (bias init; fc1 atomically accumulates on top)
// ---------------------------------------------------------------------------
__global__ __launch_bounds__(256) void init_bias8_kernel(const float* __restrict__ b,
                                                         float* __restrict__ o, int K) {
    int i = blockIdx.x * 256 + threadIdx.x;
    if (i < NKEEP * K) o[i] = b[i & (K - 1)];
}

// ---------------------------------------------------------------------------
// Kernel 4: FC1  (8 x 100352) @ (100352 x 4096) — the 1.64 GB w1 stream.
// Grid = 64 k-blocks x 16 d-slices. Thread (kq,dl): 4 w1 rows x 8 ROIs.
// ---------------------------------------------------------------------------
__global__ __launch_bounds__(256) void fc1_kernel(const float* __restrict__ w1,
                                                  const float* __restrict__ flat,
                                                  float* __restrict__ o1) {
    const int kb = blockIdx.x >> 4;       // 0..63
    const int ds = blockIdx.x & 15;       // 0..15
    const int tid = threadIdx.x;
    const int kq = tid >> 4;              // 0..15
    const int dl = tid & 15;              // 0..15 (low lane bits)
    const int k0 = kb * 64 + kq * 4;
    const int dbase = ds * DPS + dl * 4;

    const float* wp0 = w1 + (size_t)k0 * D1 + dbase;
    const float* wp1 = wp0 + D1;
    const float* wp2 = wp1 + D1;
    const float* wp3 = wp2 + D1;
    const float* fp  = flat + dbase;

    float acc[4][8];
    #pragma unroll
    for (int a = 0; a < 4; ++a)
        #pragma unroll
        for (int n = 0; n < 8; ++n) acc[a][n] = 0.f;

    for (int itn = 0; itn < DPS / 64; ++itn) {   // 98 iters
        const int off = itn * 64;
        float4 wv0 = *(const float4*)(wp0 + off);
        float4 wv1 = *(const float4*)(wp1 + off);
        float4 wv2 = *(const float4*)(wp2 + off);
        float4 wv3 = *(const float4*)(wp3 + off);
        #pragma unroll
        for (int n = 0; n < 8; ++n) {
            float4 f = *(const float4*)(fp + (size_t)n * D1 + off);
            acc[0][n] += wv0.x*f.x + wv0.y*f.y + wv0.z*f.z + wv0.w*f.w;
            acc[1][n] += wv1.x*f.x + wv1.y*f.y + wv1.z*f.z + wv1.w*f.w;
            acc[2][n] += wv2.x*f.x + wv2.y*f.y + wv2.z*f.z + wv2.w*f.w;
            acc[3][n] += wv3.x*f.x + wv3.y*f.y + wv3.z*f.z + wv3.w*f.w;
        }
    }

    // reduce across the 16 d-lanes (low 4 lane bits), then atomic into o1
    #pragma unroll
    for (int a = 0; a < 4; ++a) {
        #pragma unroll
        for (int n = 0; n < 8; ++n) {
            float v = acc[a][n];
            v += __shfl_xor(v, 1);
            v += __shfl_xor(v, 2);
            v += __shfl_xor(v, 4);
            v += __shfl_xor(v, 8);
            if (dl == 0) atomicAdd(&o1[n * K1 + k0 + a], v);
        }
    }
}

// ---------------------------------------------------------------------------
// Kernel 5: FC2 (8x4096)@(4096x4096). One wave per output row k.
// ---------------------------------------------------------------------------
__global__ __launch_bounds__(256) void fc2_kernel(const float* __restrict__ w2,
                                                  const float* __restrict__ o1,
                                                  const float* __restrict__ b2,
                                                  float* __restrict__ o2) {
    int gw   = (blockIdx.x * 256 + threadIdx.x) >> 6;
    int lane = threadIdx.x & 63;
    if (gw >= K1) return;
    const float4* wr = (const float4*)(w2 + (size_t)gw * K1);
    const float4* fo = (const float4*)o1;
    float acc[8];
    #pragma unroll
    for (int n = 0; n < 8; ++n) acc[n] = 0.f;
    for (int itn = 0; itn < K1 / 256; ++itn) {   // 16
        float4 wv = wr[itn * 64 + lane];
        #pragma unroll
        for (int n = 0; n < 8; ++n) {
            float4 f = fo[n * (K1/4) + itn * 64 + lane];
            acc[n] += wv.x*f.x + wv.y*f.y + wv.z*f.z + wv.w*f.w;
        }
    }
    #pragma unroll
    for (int n = 0; n < 8; ++n) {
        float v = acc[n];
        #pragma unroll
        for (int m = 32; m >= 1; m >>= 1) v += __shfl_xor(v, m);
        if (lane == 0) o2[n * K1 + gw] = v + b2[gw];
    }
}

// ---------------------------------------------------------------------------
// Kernel 6: heads. k<81 -> wc/bc, else wl/bl. out (8,405) row-major.
// ---------------------------------------------------------------------------
__global__ __launch_bounds__(256) void fc3_kernel(const float* __restrict__ wc,
                                                  const float* __restrict__ bc,
                                                  const float* __restrict__ wl,
                                                  const float* __restrict__ bl,
                                                  const float* __restrict__ o2,
                                                  float* __restrict__ out) {
    int gw   = (blockIdx.x * 256 + threadIdx.x) >> 6;
    int lane = threadIdx.x & 63;
    if (gw >= 405) return;
    const float* wrow; float bias;
    if (gw < 81) { wrow = wc + (size_t)gw * K1;        bias = bc[gw]; }
    else         { wrow = wl + (size_t)(gw - 81) * K1; bias = bl[gw - 81]; }
    const float4* wr = (const float4*)wrow;
    const float4* fo = (const float4*)o2;
    float acc[8];
    #pragma unroll
    for (int n = 0; n < 8; ++n) acc[n] = 0.f;
    for (int itn = 0; itn < K1 / 256; ++itn) {
        float4 wv = wr[itn * 64 + lane];
        #pragma unroll
        for (int n = 0; n < 8; ++n) {
            float4 f = fo[n * (K1/4) + itn * 64 + lane];
            acc[n] += wv.x*f.x + wv.y*f.y + wv.z*f.z + wv.w*f.w;
        }
    }
    #pragma unroll
    for (int n = 0; n < 8; ++n) {
        float v = acc[n];
        #pragma unroll
        for (int m = 32; m >= 1; m >>= 1) v += __shfl_xor(v, m);
        if (lane == 0) out[n * 405 + gw] = v + bias;
    }
}

// ---------------------------------------------------------------------------
extern "C" void kernel_launch(void* const* d_in, const int* in_sizes, int n_in,
                              void* d_out, int out_size, void* d_ws, size_t ws_size,
                              hipStream_t stream) {
    const float* feat   = (const float*)d_in[0];
    const float* rois   = (const float*)d_in[1];
    const float* scores = (const float*)d_in[2];
    const float* w1     = (const float*)d_in[3];
    const float* b1     = (const float*)d_in[4];
    const float* w2     = (const float*)d_in[5];
    const float* b2     = (const float*)d_in[6];
    const float* wc     = (const float*)d_in[7];
    const float* bc     = (const float*)d_in[8];
    const float* wl     = (const float*)d_in[9];
    const float* bl     = (const float*)d_in[10];
    float* out = (float*)d_out;

    // workspace layout (floats): [0..255] roi ints, then pooled, o1, o2
    int*   roi_out = (int*)d_ws;
    float* pooled  = (float*)d_ws + 256;
    float* o1      = pooled + (size_t)NKEEP * D1;
    float* o2      = o1 + NKEEP * K1;

    nms_sel_kernel<<<1, 256, 0, stream>>>(rois, scores, roi_out);
    roi_pool_kernel<<<(NKEEP * D1 + 255) / 256, 256, 0, stream>>>(feat, roi_out, pooled);
    init_bias8_kernel<<<(NKEEP * K1 + 255) / 256, 256, 0, stream>>>(b1, o1, K1);
    fc1_kernel<<<64 * NSLICE, 256, 0, stream>>>(w1, pooled, o1);
    fc2_kernel<<<K1 / 4, 256, 0, stream>>>(w2, o1, b2, o2);
    fc3_kernel<<<(405 * 64 + 255) / 256, 256, 0, stream>>>(wc, bc, wl, bl, o2, out);
}